// Round 1
// baseline (1426.652 us; speedup 1.0000x reference)
//
#include <hip/hip_runtime.h>

typedef __attribute__((ext_vector_type(8))) short bf16x8;
typedef __attribute__((ext_vector_type(4))) float f32x4;
typedef __attribute__((ext_vector_type(4))) unsigned short us4;

__device__ __forceinline__ unsigned short f2bf(float f) {
    unsigned u = __builtin_bit_cast(unsigned, f);
    u += 0x7FFFu + ((u >> 16) & 1u);
    return (unsigned short)(u >> 16);
}

__device__ __forceinline__ void gl_lds16(const void* g, void* l) {
    __builtin_amdgcn_global_load_lds(
        (const __attribute__((address_space(1))) unsigned int*)g,
        (__attribute__((address_space(3))) unsigned int*)l, 16, 0, 0);
}

// ---------------- cast fp32 -> bf16 (vectorized) ----------------
__global__ __launch_bounds__(256) void cast_f32_bf16(const float* __restrict__ in,
                                                     unsigned short* __restrict__ out, int n4) {
    int i = blockIdx.x * blockDim.x + threadIdx.x;
    int stride = gridDim.x * blockDim.x;
    for (; i < n4; i += stride) {
        float4 v = ((const float4*)in)[i];
        us4 o;
        o.x = f2bf(v.x); o.y = f2bf(v.y); o.z = f2bf(v.z); o.w = f2bf(v.w);
        ((us4*)out)[i] = o;
    }
}

// ---------------- weight transpose + cast: Wt[slot][n][k] = W[slot][k][n] ----------------
__global__ __launch_bounds__(256) void transpose_w(const float* __restrict__ wq,
                                                   const float* __restrict__ wk,
                                                   const float* __restrict__ wv,
                                                   const float* __restrict__ wp,
                                                   unsigned short* __restrict__ Wt) {
    int sb = blockIdx.x >> 6;     // slot 0..191
    int tile = blockIdx.x & 63;   // 8x8 tiles of 64x64
    const float* src;
    if (sb < 32)       src = wq + (size_t)sb * 262144;
    else if (sb < 96)  src = wk + (size_t)(sb - 32) * 262144;
    else if (sb < 160) src = wv + (size_t)(sb - 96) * 262144;
    else               src = wp + (size_t)(sb - 160) * 262144;
    unsigned short* dst = Wt + (size_t)sb * 262144;
    int q0 = (tile & 7) * 64, e0 = (tile >> 3) * 64;
    __shared__ float t[64][65];
    int tx = threadIdx.x & 63, ty = threadIdx.x >> 6;
    for (int i = 0; i < 16; i++) {
        int r = ty + 4 * i;
        t[r][tx] = src[(size_t)(q0 + r) * 512 + e0 + tx];
    }
    __syncthreads();
    int tx2 = threadIdx.x & 31, ty2 = threadIdx.x >> 5;
    for (int i = 0; i < 8; i++) {
        int e = ty2 + 8 * i;
        int qq = tx2 * 2;
        unsigned a = f2bf(t[qq][e]);
        unsigned bb = f2bf(t[qq + 1][e]);
        *(unsigned*)&dst[(size_t)(e0 + e) * 512 + q0 + qq] = a | (bb << 16);
    }
}

// ---------------- batched GEMM (m97 structure): C = A(2048x512) * Wt^T, bf16 MFMA ----------------
// mode 0: write Qbuf[b][h][i][d]; mode 1: Kbuf[b][h][j][d]; mode 2: Vt[b][h][d][j]
__global__ __launch_bounds__(256, 2) void gemm_qkv(const unsigned short* __restrict__ qb,
                                                   const unsigned short* __restrict__ kb,
                                                   const unsigned short* __restrict__ Wt,
                                                   unsigned short* __restrict__ Qb,
                                                   unsigned short* __restrict__ Kb,
                                                   unsigned short* __restrict__ Vt) {
    int s = blockIdx.y;
    const unsigned short* A;
    int mode, slot;
    if (s < 32)      { A = qb + (size_t)s * 1048576;        mode = 0; slot = s; }
    else if (s < 96) { A = kb + (size_t)(s - 32) * 1048576; mode = 1; slot = s - 32; }
    else             { A = kb + (size_t)(s - 96) * 1048576; mode = 2; slot = s - 96; }
    const unsigned short* B = Wt + (size_t)s * 262144;
    int tm = blockIdx.x >> 2, tn = blockIdx.x & 3;

    __shared__ __align__(16) unsigned short As[128 * 32];
    __shared__ __align__(16) unsigned short Bs[128 * 32];

    int l = threadIdx.x & 63, w = threadIdx.x >> 6;
    int lr = l >> 2, lk = (l & 3) * 8;
    const unsigned short* Ag = A + (size_t)(tm * 128) * 512;
    const unsigned short* Bg = B + (size_t)(tn * 128) * 512;
    int r0 = w * 32;

    f32x4 acc[4][4] = {};
    int wr = (w >> 1) * 64, wc = (w & 1) * 64;

    for (int k0 = 0; k0 < 512; k0 += 32) {
        __syncthreads();
        gl_lds16(Ag + (size_t)(r0 + lr) * 512 + k0 + lk,      &As[r0 * 32]);
        gl_lds16(Ag + (size_t)(r0 + 16 + lr) * 512 + k0 + lk, &As[(r0 + 16) * 32]);
        gl_lds16(Bg + (size_t)(r0 + lr) * 512 + k0 + lk,      &Bs[r0 * 32]);
        gl_lds16(Bg + (size_t)(r0 + 16 + lr) * 512 + k0 + lk, &Bs[(r0 + 16) * 32]);
        __syncthreads();
        bf16x8 aF[4], bF[4];
        for (int m = 0; m < 4; m++)
            aF[m] = *(const bf16x8*)&As[(wr + m * 16 + (l & 15)) * 32 + (l >> 4) * 8];
        for (int n = 0; n < 4; n++)
            bF[n] = *(const bf16x8*)&Bs[(wc + n * 16 + (l & 15)) * 32 + (l >> 4) * 8];
        for (int m = 0; m < 4; m++)
            for (int n = 0; n < 4; n++)
                acc[m][n] = __builtin_amdgcn_mfma_f32_16x16x32_bf16(aF[m], bF[n], acc[m][n], 0, 0, 0);
    }

    int rb = tm * 128 + wr + (l >> 4) * 4;
    int cb = tn * 128 + wc + (l & 15);
    for (int m = 0; m < 4; m++)
        for (int n = 0; n < 4; n++) {
            int col = cb + n * 16;
            int h = col >> 6, d = col & 63;
            for (int r = 0; r < 4; r++) {
                int row = rb + m * 16 + r;  // batch index
                unsigned short v = f2bf(acc[m][n][r]);
                if (mode == 0)      Qb[(((size_t)row * 8 + h) * 32 + slot) * 64 + d] = v;
                else if (mode == 1) Kb[(((size_t)row * 8 + h) * 64 + slot) * 64 + d] = v;
                else                Vt[(((size_t)row * 8 + h) * 64 + d) * 64 + slot] = v;
            }
        }
}

// ---------------- final projection GEMM: out[i][b][o] fp32 ----------------
__global__ __launch_bounds__(256, 2) void gemm_proj(const unsigned short* __restrict__ Ain,
                                                    const unsigned short* __restrict__ Wt,
                                                    float* __restrict__ out) {
    int s = blockIdx.y;
    const unsigned short* A = Ain + (size_t)s * 1048576;
    const unsigned short* B = Wt + (size_t)(160 + s) * 262144;
    int tm = blockIdx.x >> 2, tn = blockIdx.x & 3;

    __shared__ __align__(16) unsigned short As[128 * 32];
    __shared__ __align__(16) unsigned short Bs[128 * 32];

    int l = threadIdx.x & 63, w = threadIdx.x >> 6;
    int lr = l >> 2, lk = (l & 3) * 8;
    const unsigned short* Ag = A + (size_t)(tm * 128) * 512;
    const unsigned short* Bg = B + (size_t)(tn * 128) * 512;
    int r0 = w * 32;

    f32x4 acc[4][4] = {};
    int wr = (w >> 1) * 64, wc = (w & 1) * 64;

    for (int k0 = 0; k0 < 512; k0 += 32) {
        __syncthreads();
        gl_lds16(Ag + (size_t)(r0 + lr) * 512 + k0 + lk,      &As[r0 * 32]);
        gl_lds16(Ag + (size_t)(r0 + 16 + lr) * 512 + k0 + lk, &As[(r0 + 16) * 32]);
        gl_lds16(Bg + (size_t)(r0 + lr) * 512 + k0 + lk,      &Bs[r0 * 32]);
        gl_lds16(Bg + (size_t)(r0 + 16 + lr) * 512 + k0 + lk, &Bs[(r0 + 16) * 32]);
        __syncthreads();
        bf16x8 aF[4], bF[4];
        for (int m = 0; m < 4; m++)
            aF[m] = *(const bf16x8*)&As[(wr + m * 16 + (l & 15)) * 32 + (l >> 4) * 8];
        for (int n = 0; n < 4; n++)
            bF[n] = *(const bf16x8*)&Bs[(wc + n * 16 + (l & 15)) * 32 + (l >> 4) * 8];
        for (int m = 0; m < 4; m++)
            for (int n = 0; n < 4; n++)
                acc[m][n] = __builtin_amdgcn_mfma_f32_16x16x32_bf16(aF[m], bF[n], acc[m][n], 0, 0, 0);
    }

    int rb = tm * 128 + wr + (l >> 4) * 4;
    int cb = tn * 128 + wc + (l & 15);
    for (int m = 0; m < 4; m++)
        for (int n = 0; n < 4; n++) {
            int col = cb + n * 16;
            for (int r = 0; r < 4; r++) {
                int row = rb + m * 16 + r;
                out[((size_t)s * 2048 + row) * 512 + col] = acc[m][n][r];
            }
        }
}

// ---------------- attention core: one wave per (b,h) ----------------
__global__ __launch_bounds__(256, 2) void attn_k(const unsigned short* __restrict__ Qb,
                                                 const unsigned short* __restrict__ Kb,
                                                 const unsigned short* __restrict__ Vt,
                                                 unsigned short* __restrict__ Aout) {
    __shared__ __align__(16) unsigned short pl[4][32 * 72];
    int w = threadIdx.x >> 6, l = threadIdx.x & 63;
    int g = blockIdx.x * 4 + w;
    int b = g >> 3, h = g & 7;
    const unsigned short* Q = Qb + (size_t)(b * 8 + h) * 2048;  // [32][64]
    const unsigned short* K = Kb + (size_t)(b * 8 + h) * 4096;  // [64][64]
    const unsigned short* V = Vt + (size_t)(b * 8 + h) * 4096;  // [64(d)][64(j)]
    int lr = l & 15, lc = l >> 4;

    bf16x8 aQ[2][2], bK[4][2];
    for (int m = 0; m < 2; m++)
        for (int kc = 0; kc < 2; kc++)
            aQ[m][kc] = *(const bf16x8*)&Q[(m * 16 + lr) * 64 + kc * 32 + lc * 8];
    for (int n = 0; n < 4; n++)
        for (int kc = 0; kc < 2; kc++)
            bK[n][kc] = *(const bf16x8*)&K[(n * 16 + lr) * 64 + kc * 32 + lc * 8];

    f32x4 acc[2][4] = {};
    for (int kc = 0; kc < 2; kc++)
        for (int m = 0; m < 2; m++)
            for (int n = 0; n < 4; n++)
                acc[m][n] = __builtin_amdgcn_mfma_f32_16x16x32_bf16(aQ[m][kc], bK[n][kc], acc[m][n], 0, 0, 0);

    const float sc = 0.18033688011112042f;  // log2(e)/8
    for (int m = 0; m < 2; m++) {
        for (int r = 0; r < 4; r++) {
            float v = acc[m][0][r];
            for (int n = 1; n < 4; n++) v = fmaxf(v, acc[m][n][r]);
            for (int sh = 1; sh < 16; sh <<= 1) v = fmaxf(v, __shfl_xor(v, sh));
            float ssum = 0.f;
            for (int n = 0; n < 4; n++) {
                float p = exp2f((acc[m][n][r] - v) * sc);
                acc[m][n][r] = p;
                ssum += p;
            }
            for (int sh = 1; sh < 16; sh <<= 1) ssum += __shfl_xor(ssum, sh);
            float inv = 1.0f / ssum;
            for (int n = 0; n < 4; n++)
                pl[w][(m * 16 + lc * 4 + r) * 72 + n * 16 + lr] = f2bf(acc[m][n][r] * inv);
        }
    }
    __syncthreads();

    bf16x8 aP[2][2], bV[4][2];
    for (int m = 0; m < 2; m++)
        for (int kc = 0; kc < 2; kc++)
            aP[m][kc] = *(const bf16x8*)&pl[w][(m * 16 + lr) * 72 + kc * 32 + lc * 8];
    for (int n = 0; n < 4; n++)
        for (int kc = 0; kc < 2; kc++)
            bV[n][kc] = *(const bf16x8*)&V[(n * 16 + lr) * 64 + kc * 32 + lc * 8];

    f32x4 o[2][4] = {};
    for (int kc = 0; kc < 2; kc++)
        for (int m = 0; m < 2; m++)
            for (int n = 0; n < 4; n++)
                o[m][n] = __builtin_amdgcn_mfma_f32_16x16x32_bf16(aP[m][kc], bV[n][kc], o[m][n], 0, 0, 0);

    for (int m = 0; m < 2; m++)
        for (int n = 0; n < 4; n++)
            for (int r = 0; r < 4; r++) {
                int i = m * 16 + lc * 4 + r;
                int d = n * 16 + lr;
                Aout[(size_t)i * 1048576 + (size_t)b * 512 + h * 64 + d] = f2bf(o[m][n][r]);
            }
}

extern "C" void kernel_launch(void* const* d_in, const int* in_sizes, int n_in,
                              void* d_out, int out_size, void* d_ws, size_t ws_size,
                              hipStream_t stream) {
    const float* q  = (const float*)d_in[0];
    const float* k  = (const float*)d_in[1];
    const float* wq = (const float*)d_in[2];
    const float* wk = (const float*)d_in[3];
    const float* wv = (const float*)d_in[4];
    const float* wp = (const float*)d_in[5];

    char* ws = (char*)d_ws;
    unsigned short* qb = (unsigned short*)(ws);                          // 64 MiB
    unsigned short* kb = (unsigned short*)(ws + ((size_t)64 << 20));     // 128 MiB
    unsigned short* Wt = (unsigned short*)(ws + ((size_t)192 << 20));    // 96 MiB
    unsigned short* Qb = (unsigned short*)(ws + ((size_t)288 << 20));    // 64 MiB
    unsigned short* Kb = (unsigned short*)(ws + ((size_t)352 << 20));    // 128 MiB
    unsigned short* Vt = (unsigned short*)(ws + ((size_t)480 << 20));    // 128 MiB
    unsigned short* Aout = qb;  // reuse: qb dead after gemm_qkv
    float* out = (float*)d_out;

    hipLaunchKernelGGL(cast_f32_bf16, dim3(2048), dim3(256), 0, stream, q, qb, 32 * 2048 * 512 / 4);
    hipLaunchKernelGGL(cast_f32_bf16, dim3(2048), dim3(256), 0, stream, k, kb, 64 * 2048 * 512 / 4);
    hipLaunchKernelGGL(transpose_w, dim3(192 * 64), dim3(256), 0, stream, wq, wk, wv, wp, Wt);
    hipLaunchKernelGGL(gemm_qkv, dim3(64, 160), dim3(256), 0, stream, qb, kb, Wt, Qb, Kb, Vt);
    hipLaunchKernelGGL(attn_k, dim3(4096), dim3(256), 0, stream, Qb, Kb, Vt, Aout);
    hipLaunchKernelGGL(gemm_proj, dim3(64, 32), dim3(256), 0, stream, Aout, Wt, out);
}

// Round 2
// 613.806 us; speedup vs baseline: 2.3243x; 2.3243x over previous
//
#include <hip/hip_runtime.h>

typedef __attribute__((ext_vector_type(8))) short bf16x8;
typedef __attribute__((ext_vector_type(4))) float f32x4;
typedef __attribute__((ext_vector_type(4))) unsigned short us4;

__device__ __forceinline__ unsigned short f2bf(float f) {
    unsigned u = __builtin_bit_cast(unsigned, f);
    u += 0x7FFFu + ((u >> 16) & 1u);
    return (unsigned short)(u >> 16);
}

__device__ __forceinline__ void gl_lds16(const void* g, void* l) {
    __builtin_amdgcn_global_load_lds(
        (const __attribute__((address_space(1))) unsigned int*)g,
        (__attribute__((address_space(3))) unsigned int*)l, 16, 0, 0);
}

// ---------------- cast fp32 -> bf16 (vectorized) ----------------
__global__ __launch_bounds__(256) void cast_f32_bf16(const float* __restrict__ in,
                                                     unsigned short* __restrict__ out, int n4) {
    int i = blockIdx.x * blockDim.x + threadIdx.x;
    int stride = gridDim.x * blockDim.x;
    for (; i < n4; i += stride) {
        float4 v = ((const float4*)in)[i];
        us4 o;
        o.x = f2bf(v.x); o.y = f2bf(v.y); o.z = f2bf(v.z); o.w = f2bf(v.w);
        ((us4*)out)[i] = o;
    }
}

// ---------------- weight transpose + cast: Wt[slot][n][k] = W[slot][k][n] ----------------
__global__ __launch_bounds__(256) void transpose_w(const float* __restrict__ wq,
                                                   const float* __restrict__ wk,
                                                   const float* __restrict__ wv,
                                                   const float* __restrict__ wp,
                                                   unsigned short* __restrict__ Wt) {
    int sb = blockIdx.x >> 6;     // slot 0..191
    int tile = blockIdx.x & 63;   // 8x8 tiles of 64x64
    const float* src;
    if (sb < 32)       src = wq + (size_t)sb * 262144;
    else if (sb < 96)  src = wk + (size_t)(sb - 32) * 262144;
    else if (sb < 160) src = wv + (size_t)(sb - 96) * 262144;
    else               src = wp + (size_t)(sb - 160) * 262144;
    unsigned short* dst = Wt + (size_t)sb * 262144;
    int q0 = (tile & 7) * 64, e0 = (tile >> 3) * 64;
    __shared__ float t[64][65];
    int tx = threadIdx.x & 63, ty = threadIdx.x >> 6;
    for (int i = 0; i < 16; i++) {
        int r = ty + 4 * i;
        t[r][tx] = src[(size_t)(q0 + r) * 512 + e0 + tx];
    }
    __syncthreads();
    int tx2 = threadIdx.x & 31, ty2 = threadIdx.x >> 5;
    for (int i = 0; i < 8; i++) {
        int e = ty2 + 8 * i;
        int qq = tx2 * 2;
        unsigned a = f2bf(t[qq][e]);
        unsigned bb = f2bf(t[qq + 1][e]);
        *(unsigned*)&dst[(size_t)(e0 + e) * 512 + q0 + qq] = a | (bb << 16);
    }
}

// ---------------- batched GEMM: C[slot][2048][512] = A(2048x512) * Wt^T, bf16 out ----------------
__global__ __launch_bounds__(256, 2) void gemm_qkv(const unsigned short* __restrict__ qb,
                                                   const unsigned short* __restrict__ kb,
                                                   const unsigned short* __restrict__ Wt,
                                                   unsigned short* __restrict__ Qs,
                                                   unsigned short* __restrict__ Ks,
                                                   unsigned short* __restrict__ Vs) {
    __shared__ __align__(16) unsigned short lds[2][2][8192];  // dbuf x (A,B) x 128x64
    int s = blockIdx.y;
    const unsigned short* A;
    unsigned short* Cw;
    if (s < 32)      { A = qb + (size_t)s * 1048576;        Cw = Qs + (size_t)s * 1048576; }
    else if (s < 96) { A = kb + (size_t)(s - 32) * 1048576; Cw = Ks + (size_t)(s - 32) * 1048576; }
    else             { A = kb + (size_t)(s - 96) * 1048576; Cw = Vs + (size_t)(s - 96) * 1048576; }
    const unsigned short* B = Wt + (size_t)s * 262144;
    int tm = blockIdx.x >> 2, tn = blockIdx.x & 3;
    int l = threadIdx.x & 63, w = threadIdx.x >> 6;
    const unsigned short* Ag = A + (size_t)(tm * 128) * 512;
    const unsigned short* Bg = B + (size_t)(tn * 128) * 512;
    int wr = (w >> 1) * 64, wc = (w & 1) * 64;
    int srcs = ((l & 7) ^ (l >> 3)) * 8;   // pre-swizzled source k-slot (XOR with row&7)

    f32x4 acc[4][4] = {};

#define STAGE(bufi, k0)                                                            \
    for (int p = 0; p < 4; p++) {                                                  \
        int row = w * 32 + p * 8 + (l >> 3);                                       \
        gl_lds16(Ag + (size_t)row * 512 + (k0) + srcs, &lds[bufi][0][(w*32+p*8)*64]); \
        gl_lds16(Bg + (size_t)row * 512 + (k0) + srcs, &lds[bufi][1][(w*32+p*8)*64]); \
    }

    STAGE(0, 0)
    __syncthreads();
    for (int t = 0; t < 8; t++) {
        int cur = t & 1;
        if (t < 7) { STAGE(cur ^ 1, (t + 1) * 64) }
        bf16x8 aF[2][4], bF[2][4];
        for (int kc = 0; kc < 2; kc++) {
            int sp = ((kc * 4 + (l >> 4)) ^ (l & 7)) * 8;  // swizzled read slot
            for (int m = 0; m < 4; m++)
                aF[kc][m] = *(const bf16x8*)&lds[cur][0][(wr + m * 16 + (l & 15)) * 64 + sp];
            for (int n = 0; n < 4; n++)
                bF[kc][n] = *(const bf16x8*)&lds[cur][1][(wc + n * 16 + (l & 15)) * 64 + sp];
        }
        for (int kc = 0; kc < 2; kc++)
            for (int m = 0; m < 4; m++)
                for (int n = 0; n < 4; n++)
                    acc[m][n] = __builtin_amdgcn_mfma_f32_16x16x32_bf16(aF[kc][m], bF[kc][n], acc[m][n], 0, 0, 0);
        __syncthreads();
    }
#undef STAGE

    // epilogue: stage C-tile bf16 in LDS, emit full-line coalesced stores
    unsigned short* Cs = &lds[0][0][0];  // [128][136]
    for (int m = 0; m < 4; m++)
        for (int n = 0; n < 4; n++)
            for (int r = 0; r < 4; r++)
                Cs[(wr + m * 16 + (l >> 4) * 4 + r) * 136 + wc + n * 16 + (l & 15)] = f2bf(acc[m][n][r]);
    __syncthreads();
    for (int rnd = 0; rnd < 8; rnd++) {
        int row = rnd * 16 + (threadIdx.x >> 4);
        int c8 = (threadIdx.x & 15) * 8;
        bf16x8 v = *(const bf16x8*)&Cs[row * 136 + c8];
        *(bf16x8*)&Cw[(size_t)(tm * 128 + row) * 512 + tn * 128 + c8] = v;
    }
}

// ---------------- final projection GEMM: out[slot][2048][512] fp32 ----------------
__global__ __launch_bounds__(256, 2) void gemm_proj(const unsigned short* __restrict__ Ain,
                                                    const unsigned short* __restrict__ Wt,
                                                    float* __restrict__ out) {
    __shared__ __align__(16) unsigned short lds[2][2][8192];
    int s = blockIdx.y;
    const unsigned short* A = Ain + (size_t)s * 1048576;
    const unsigned short* B = Wt + (size_t)(160 + s) * 262144;
    int tm = blockIdx.x >> 2, tn = blockIdx.x & 3;
    int l = threadIdx.x & 63, w = threadIdx.x >> 6;
    const unsigned short* Ag = A + (size_t)(tm * 128) * 512;
    const unsigned short* Bg = B + (size_t)(tn * 128) * 512;
    int wr = (w >> 1) * 64, wc = (w & 1) * 64;
    int srcs = ((l & 7) ^ (l >> 3)) * 8;

    f32x4 acc[4][4] = {};

#define STAGE(bufi, k0)                                                            \
    for (int p = 0; p < 4; p++) {                                                  \
        int row = w * 32 + p * 8 + (l >> 3);                                       \
        gl_lds16(Ag + (size_t)row * 512 + (k0) + srcs, &lds[bufi][0][(w*32+p*8)*64]); \
        gl_lds16(Bg + (size_t)row * 512 + (k0) + srcs, &lds[bufi][1][(w*32+p*8)*64]); \
    }

    STAGE(0, 0)
    __syncthreads();
    for (int t = 0; t < 8; t++) {
        int cur = t & 1;
        if (t < 7) { STAGE(cur ^ 1, (t + 1) * 64) }
        bf16x8 aF[2][4], bF[2][4];
        for (int kc = 0; kc < 2; kc++) {
            int sp = ((kc * 4 + (l >> 4)) ^ (l & 7)) * 8;
            for (int m = 0; m < 4; m++)
                aF[kc][m] = *(const bf16x8*)&lds[cur][0][(wr + m * 16 + (l & 15)) * 64 + sp];
            for (int n = 0; n < 4; n++)
                bF[kc][n] = *(const bf16x8*)&lds[cur][1][(wc + n * 16 + (l & 15)) * 64 + sp];
        }
        for (int kc = 0; kc < 2; kc++)
            for (int m = 0; m < 4; m++)
                for (int n = 0; n < 4; n++)
                    acc[m][n] = __builtin_amdgcn_mfma_f32_16x16x32_bf16(aF[kc][m], bF[kc][n], acc[m][n], 0, 0, 0);
        __syncthreads();
    }
#undef STAGE

    // epilogue: two half-tile fp32 passes through LDS, full 512B-row stores
    float* Cf = (float*)&lds[0][0][0];  // [64][132]
    for (int pass = 0; pass < 2; pass++) {
        if (wr == pass * 64) {
            for (int m = 0; m < 4; m++)
                for (int n = 0; n < 4; n++)
                    for (int r = 0; r < 4; r++)
                        Cf[(m * 16 + (l >> 4) * 4 + r) * 132 + wc + n * 16 + (l & 15)] = acc[m][n][r];
        }
        __syncthreads();
        for (int rnd = 0; rnd < 8; rnd++) {
            int row = rnd * 8 + (threadIdx.x >> 5);
            int c4 = (threadIdx.x & 31) * 4;
            float4 v = *(const float4*)&Cf[row * 132 + c4];
            *(float4*)&out[(size_t)s * 1048576 + (size_t)(tm * 128 + pass * 64 + row) * 512 + tn * 128 + c4] = v;
        }
        __syncthreads();
    }
}

// ---------------- attention core: one wave per (b,h), slot-major inputs ----------------
__global__ __launch_bounds__(256) void attn_k(const unsigned short* __restrict__ Qs,
                                              const unsigned short* __restrict__ Ks,
                                              const unsigned short* __restrict__ Vs,
                                              unsigned short* __restrict__ Aout) {
    __shared__ __align__(16) unsigned short pl[4][32 * 72];
    __shared__ __align__(16) unsigned short vt[4][64 * 88];
    const size_t SL = 1048576;  // slot stride (elems)
    int w = threadIdx.x >> 6, l = threadIdx.x & 63;
    int g = blockIdx.x * 4 + w;
    int b = g >> 3, h = g & 7;
    const unsigned short* Qp = Qs + (size_t)b * 512 + h * 64;
    const unsigned short* Kp = Ks + (size_t)b * 512 + h * 64;
    const unsigned short* Vp = Vs + (size_t)b * 512 + h * 64;
    int lr = l & 15, lc = l >> 4;
    unsigned short* vtw = vt[w];

    // stage V^T [d][j] into LDS (stride 88 keeps 16B align + bank spread on reads)
    for (int jr = 0; jr < 64; jr += 8) {
        int j = jr + (l >> 3), d0 = (l & 7) * 8;
        bf16x8 v = *(const bf16x8*)&Vp[(size_t)j * SL + d0];
        for (int e = 0; e < 8; e++) vtw[(d0 + e) * 88 + j] = (unsigned short)v[e];
    }

    bf16x8 aQ[2][2], bK[4][2];
    for (int m = 0; m < 2; m++)
        for (int kc = 0; kc < 2; kc++)
            aQ[m][kc] = *(const bf16x8*)&Qp[(size_t)(m * 16 + lr) * SL + kc * 32 + lc * 8];
    for (int n = 0; n < 4; n++)
        for (int kc = 0; kc < 2; kc++)
            bK[n][kc] = *(const bf16x8*)&Kp[(size_t)(n * 16 + lr) * SL + kc * 32 + lc * 8];

    f32x4 acc[2][4] = {};
    for (int kc = 0; kc < 2; kc++)
        for (int m = 0; m < 2; m++)
            for (int n = 0; n < 4; n++)
                acc[m][n] = __builtin_amdgcn_mfma_f32_16x16x32_bf16(aQ[m][kc], bK[n][kc], acc[m][n], 0, 0, 0);

    const float sc = 0.18033688011112042f;  // log2(e)/8
    for (int m = 0; m < 2; m++) {
        for (int r = 0; r < 4; r++) {
            float v = acc[m][0][r];
            for (int n = 1; n < 4; n++) v = fmaxf(v, acc[m][n][r]);
            for (int sh = 1; sh < 16; sh <<= 1) v = fmaxf(v, __shfl_xor(v, sh));
            float ssum = 0.f;
            for (int n = 0; n < 4; n++) {
                float p = exp2f((acc[m][n][r] - v) * sc);
                acc[m][n][r] = p;
                ssum += p;
            }
            for (int sh = 1; sh < 16; sh <<= 1) ssum += __shfl_xor(ssum, sh);
            float inv = 1.0f / ssum;
            for (int n = 0; n < 4; n++)
                pl[w][(m * 16 + lc * 4 + r) * 72 + n * 16 + lr] = f2bf(acc[m][n][r] * inv);
        }
    }

    bf16x8 aP[2][2], bV[4][2];
    for (int m = 0; m < 2; m++)
        for (int kc = 0; kc < 2; kc++)
            aP[m][kc] = *(const bf16x8*)&pl[w][(m * 16 + lr) * 72 + kc * 32 + lc * 8];
    for (int n = 0; n < 4; n++)
        for (int kc = 0; kc < 2; kc++)
            bV[n][kc] = *(const bf16x8*)&vtw[(n * 16 + lr) * 88 + kc * 32 + lc * 8];

    f32x4 o[2][4] = {};
    for (int kc = 0; kc < 2; kc++)
        for (int m = 0; m < 2; m++)
            for (int n = 0; n < 4; n++)
                o[m][n] = __builtin_amdgcn_mfma_f32_16x16x32_bf16(aP[m][kc], bV[n][kc], o[m][n], 0, 0, 0);

    // stage O per-wave in LDS (reuse vtw), write full-line 128B rows
    for (int m = 0; m < 2; m++)
        for (int n = 0; n < 4; n++)
            for (int r = 0; r < 4; r++)
                vtw[(m * 16 + lc * 4 + r) * 88 + n * 16 + lr] = f2bf(o[m][n][r]);
    for (int rnd = 0; rnd < 4; rnd++) {
        int i = rnd * 8 + (l >> 3), d0 = (l & 7) * 8;
        bf16x8 v = *(const bf16x8*)&vtw[i * 88 + d0];
        *(bf16x8*)&Aout[(size_t)i * SL + (size_t)b * 512 + h * 64 + d0] = v;
    }
}

extern "C" void kernel_launch(void* const* d_in, const int* in_sizes, int n_in,
                              void* d_out, int out_size, void* d_ws, size_t ws_size,
                              hipStream_t stream) {
    const float* q  = (const float*)d_in[0];
    const float* k  = (const float*)d_in[1];
    const float* wq = (const float*)d_in[2];
    const float* wk = (const float*)d_in[3];
    const float* wv = (const float*)d_in[4];
    const float* wp = (const float*)d_in[5];

    char* ws = (char*)d_ws;
    unsigned short* qb = (unsigned short*)(ws);                          // 64 MiB
    unsigned short* kb = (unsigned short*)(ws + ((size_t)64 << 20));     // 128 MiB
    unsigned short* Wt = (unsigned short*)(ws + ((size_t)192 << 20));    // 96 MiB
    unsigned short* Qs = (unsigned short*)(ws + ((size_t)288 << 20));    // 64 MiB
    unsigned short* Ks = (unsigned short*)(ws + ((size_t)352 << 20));    // 128 MiB
    unsigned short* Vs = (unsigned short*)(ws + ((size_t)480 << 20));    // 128 MiB
    unsigned short* Aout = qb;  // reuse: qb dead after gemm_qkv
    float* out = (float*)d_out;

    hipLaunchKernelGGL(cast_f32_bf16, dim3(2048), dim3(256), 0, stream, q, qb, 32 * 2048 * 512 / 4);
    hipLaunchKernelGGL(cast_f32_bf16, dim3(2048), dim3(256), 0, stream, k, kb, 64 * 2048 * 512 / 4);
    hipLaunchKernelGGL(transpose_w, dim3(192 * 64), dim3(256), 0, stream, wq, wk, wv, wp, Wt);
    hipLaunchKernelGGL(gemm_qkv, dim3(64, 160), dim3(256), 0, stream, qb, kb, Wt, Qs, Ks, Vs);
    hipLaunchKernelGGL(attn_k, dim3(4096), dim3(256), 0, stream, Qs, Ks, Vs, Aout);
    hipLaunchKernelGGL(gemm_proj, dim3(64, 32), dim3(256), 0, stream, Aout, Wt, out);
}